// Round 8
// baseline (754.825 us; speedup 1.0000x reference)
//
#include <hip/hip_runtime.h>
#include <stdint.h>

typedef __attribute__((ext_vector_type(8))) short short8;
typedef __attribute__((ext_vector_type(4))) float f32x4;
typedef __attribute__((ext_vector_type(4))) _Float16 h16x4;

#define LOG2E 1.4426950408889634f

// workspace layout (bytes) — ws ~1 GB, we use ~80 MB
#define OFF_WTT   0u          // W tiled bf16 [8][4][256][8]        = 131072
#define OFF_WHTB  131072u     // Wh tiled bf16 [256][4][256][8]     = 4194304
#define OFF_FSRC  12713984u   // f_src f32 [8192]
#define OFF_FDST  12746752u   // f_dst f32 [8192]
#define OFF_MKEY  12779520u   // max-key u32
#define OFF_LP    12779584u   // L partials f32 [16][8192]          = 524288
#define OFF_ACCH  13303872u   // ACC partials f16 [16][8192][256]   = 67108864

__device__ __forceinline__ unsigned short f2bf(float f) {
    union { float f; unsigned int i; } v; v.f = f;
    unsigned int u = v.i;
    return (unsigned short)((u + 0x7FFFu + ((u >> 16) & 1u)) >> 16);
}

// ---------------- K0: W (f32) -> tiled W^T (bf16), init max-key ----------------
__global__ void k0_init(const float* __restrict__ W,
                        unsigned short* __restrict__ WTt,
                        unsigned int* __restrict__ Mkey) {
    int idx = blockIdx.x * 256 + threadIdx.x;   // 65536 = i*256+o
    int i = idx >> 8, o = idx & 255;
    WTt[(i >> 5) * 8192 + ((i >> 3) & 3) * 2048 + o * 8 + (i & 7)] = f2bf(W[idx]);
    if (idx == 0) *Mkey = 0u;
}

// ---------------- K1: Wh = X@W, write tiled Wh (bf16), f_src/f_dst, global max ----
__global__ __launch_bounds__(256, 2)
void k1_stage1(const float* __restrict__ X,
               const unsigned short* __restrict__ WTt,
               const float* __restrict__ a_src,
               const float* __restrict__ a_dst,
               unsigned short* __restrict__ WhTb,
               float* __restrict__ f_src,
               float* __restrict__ f_dst,
               unsigned int* __restrict__ Mkey) {
    __shared__ __align__(16) unsigned short Bt[8192];   // 16 KB tile
    __shared__ float fsum[64];
    const int t = threadIdx.x, w = t >> 6, lane = t & 63, l15 = lane & 15, q = lane >> 4;
    const int rg = w & 1, cg = w >> 1;
    const int i0 = blockIdx.x * 32;
    const int arow = i0 + rg * 16 + l15;

    if (t < 64) fsum[t] = 0.f;

    float as[8], ad[8];
#pragma unroll
    for (int ci = 0; ci < 8; ++ci) {
        int col = cg * 128 + ci * 16 + l15;
        as[ci] = a_src[col]; ad[ci] = a_dst[col];
    }

    f32x4 acc[8];
#pragma unroll
    for (int ci = 0; ci < 8; ++ci) acc[ci] = (f32x4)0.f;

    for (int ks = 0; ks < 8; ++ks) {
        __syncthreads();
        {
            const uint4* src = (const uint4*)(WTt + ks * 8192);
            uint4* dst = (uint4*)Bt;
            dst[t] = src[t]; dst[256 + t] = src[256 + t];
            dst[512 + t] = src[512 + t]; dst[768 + t] = src[768 + t];
        }
        __syncthreads();
        const float* xp = X + (size_t)arow * 256 + ks * 32 + q * 8;
        float4 xa = *(const float4*)xp;
        float4 xb = *(const float4*)(xp + 4);
        short8 a;
        a[0] = (short)f2bf(xa.x); a[1] = (short)f2bf(xa.y);
        a[2] = (short)f2bf(xa.z); a[3] = (short)f2bf(xa.w);
        a[4] = (short)f2bf(xb.x); a[5] = (short)f2bf(xb.y);
        a[6] = (short)f2bf(xb.z); a[7] = (short)f2bf(xb.w);
#pragma unroll
        for (int ci = 0; ci < 8; ++ci) {
            short8 b = *(const short8*)((const char*)Bt + q * 4096 + (cg * 128 + ci * 16 + l15) * 16);
            acc[ci] = __builtin_amdgcn_mfma_f32_16x16x32_bf16(a, b, acc[ci], 0, 0, 0);
        }
    }

#pragma unroll
    for (int ci = 0; ci < 8; ++ci) {
        int col = cg * 128 + ci * 16 + l15;
        ushort4 v;
        v.x = f2bf(acc[ci][0]); v.y = f2bf(acc[ci][1]);
        v.z = f2bf(acc[ci][2]); v.w = f2bf(acc[ci][3]);
        size_t flat = (size_t)(i0 >> 5) * 8192 + (size_t)(rg * 2 + (q >> 1)) * 2048
                      + (size_t)col * 8 + (q & 1) * 4;
        *(ushort4*)(WhTb + flat) = v;
    }

#pragma unroll
    for (int reg = 0; reg < 4; ++reg) {
        float ps = 0.f, pd = 0.f;
#pragma unroll
        for (int ci = 0; ci < 8; ++ci) {
            ps += acc[ci][reg] * as[ci];
            pd += acc[ci][reg] * ad[ci];
        }
#pragma unroll
        for (int m = 1; m < 16; m <<= 1) {
            ps += __shfl_xor(ps, m, 64);
            pd += __shfl_xor(pd, m, 64);
        }
        if (l15 == 0) {
            atomicAdd(&fsum[rg * 16 + q * 4 + reg], ps);
            atomicAdd(&fsum[32 + rg * 16 + q * 4 + reg], pd);
        }
    }
    __syncthreads();
    if (t < 32) {
        int row = i0 + t;
        float ps = fsum[t], pd = fsum[32 + t];
        f_src[row] = ps;
        f_dst[row] = pd;
        union { float f; unsigned int u; } cv; cv.f = pd;
        unsigned int key = (cv.u & 0x80000000u) ? ~cv.u : (cv.u | 0x80000000u);
        atomicMax(Mkey, key);
    }
}

// ---------------- K2: fused mask+softmax+P@Wh, no LDS/barriers, 4 blocks/CU ----
// grid (64 i-tiles x 16 j-chunks), 256 thr = 4 waves; wave = 32 rows x 256 cols,
// 512 j per block (16 iters). adj streamed HBM->regs once in A-frag order;
// B-frags direct from tiled WhTb (L2). High occupancy hides load latency.
__global__ __launch_bounds__(256, 4)
void k2_fused(const int* __restrict__ adj,
              const unsigned short* __restrict__ WhTb,
              const float* __restrict__ f_src,
              const float* __restrict__ f_dst,
              const unsigned int* __restrict__ Mkey,
              float* __restrict__ Lp,
              _Float16* __restrict__ ACCh) {
    const int t = threadIdx.x, w = t >> 6, lane = t & 63, l15 = lane & 15, q = lane >> 4;
    const int i0 = blockIdx.x * 128;
    const int jc = blockIdx.y;
    const int jb0 = jc * 512;    // j base
    const int jw0 = jc * 16;     // 32-j tile base

    unsigned int key = *Mkey;
    union { unsigned int u; float f; } mv;
    mv.u = (key & 0x80000000u) ? (key & 0x7FFFFFFFu) : ~key;
    const float Mf = mv.f;
    const int rA = i0 + w * 32 + l15;
    const float fsA = f_src[rA], fsB = f_src[rA + 16];
    float vA = fsA + Mf; const float mcA = fmaxf(vA, 0.2f * vA) * LOG2E;
    float vB = fsB + Mf; const float mcB = fmaxf(vB, 0.2f * vB) * LOG2E;

    const int* adjA = adj + (size_t)rA * 8192 + jb0 + q * 8;
    const int* adjB = adj + (size_t)(rA + 16) * 8192 + jb0 + q * 8;
    const float* fdp = f_dst + jb0 + q * 8;
    const unsigned short* Bbase = WhTb + (size_t)jw0 * 8192 + q * 2048 + l15 * 8;

    f32x4 accA[16], accB[16];
#pragma unroll
    for (int ci = 0; ci < 16; ++ci) { accA[ci] = (f32x4)0.f; accB[ci] = (f32x4)0.f; }
    float lsA = 0.f, lsB = 0.f;

    // prefetch js=0 adj/fd
    int4 pA0 = *(const int4*)(adjA);
    int4 pA1 = *(const int4*)(adjA + 4);
    int4 pB0 = *(const int4*)(adjB);
    int4 pB1 = *(const int4*)(adjB + 4);
    float4 pf0 = *(const float4*)(fdp);
    float4 pf1 = *(const float4*)(fdp + 4);

    for (int js = 0; js < 16; ++js) {
        float fdv[8] = { pf0.x, pf0.y, pf0.z, pf0.w, pf1.x, pf1.y, pf1.z, pf1.w };
        int aAv[8] = { pA0.x, pA0.y, pA0.z, pA0.w, pA1.x, pA1.y, pA1.z, pA1.w };
        int aBv[8] = { pB0.x, pB0.y, pB0.z, pB0.w, pB1.x, pB1.y, pB1.z, pB1.w };

        // P fragments: A-layout A[m=l15][k=q*8+j]
        short8 fragA, fragB;
#pragma unroll
        for (int k = 0; k < 8; ++k) {
            float tA = fsA + fdv[k];
            float eA = fmaxf(tA, 0.2f * tA);
            float pA = __builtin_amdgcn_exp2f(__builtin_fmaf(eA, LOG2E, -mcA));
            pA = (aAv[k] > 0) ? pA : 0.f;
            lsA += pA; fragA[k] = (short)f2bf(pA);
            float tB = fsB + fdv[k];
            float eB = fmaxf(tB, 0.2f * tB);
            float pB = __builtin_amdgcn_exp2f(__builtin_fmaf(eB, LOG2E, -mcB));
            pB = (aBv[k] > 0) ? pB : 0.f;
            lsB += pB; fragB[k] = (short)f2bf(pB);
        }

        // prefetch next-iter adj/fd (hidden under MFMAs)
        int jn = (js + 1) & 15;
        pA0 = *(const int4*)(adjA + jn * 32);
        pA1 = *(const int4*)(adjA + jn * 32 + 4);
        pB0 = *(const int4*)(adjB + jn * 32);
        pB1 = *(const int4*)(adjB + jn * 32 + 4);
        pf0 = *(const float4*)(fdp + jn * 32);
        pf1 = *(const float4*)(fdp + jn * 32 + 4);

        // B-frags direct from L2 (dense 256B chunks), interleaved with MFMA
        const unsigned short* bp = Bbase + (size_t)js * 8192;
        short8 bf[8];
#pragma unroll
        for (int ci = 0; ci < 8; ++ci) bf[ci] = *(const short8*)(bp + ci * 128);
#pragma unroll
        for (int ci = 0; ci < 8; ++ci) {
            accA[ci] = __builtin_amdgcn_mfma_f32_16x16x32_bf16(fragA, bf[ci], accA[ci], 0, 0, 0);
            accB[ci] = __builtin_amdgcn_mfma_f32_16x16x32_bf16(fragB, bf[ci], accB[ci], 0, 0, 0);
        }
#pragma unroll
        for (int ci = 0; ci < 8; ++ci) bf[ci] = *(const short8*)(bp + (ci + 8) * 128);
#pragma unroll
        for (int ci = 0; ci < 8; ++ci) {
            accA[8 + ci] = __builtin_amdgcn_mfma_f32_16x16x32_bf16(fragA, bf[ci], accA[8 + ci], 0, 0, 0);
            accB[8 + ci] = __builtin_amdgcn_mfma_f32_16x16x32_bf16(fragB, bf[ci], accB[8 + ci], 0, 0, 0);
        }
    }

    // row-sums: quads hold disjoint j; lanes 0-15 end with row totals
    lsA += __shfl_xor(lsA, 16, 64); lsA += __shfl_xor(lsA, 32, 64);
    lsB += __shfl_xor(lsB, 16, 64); lsB += __shfl_xor(lsB, 32, 64);
    if (lane < 16) {
        Lp[(size_t)jc * 8192 + i0 + w * 32 + lane] = lsA;
        Lp[(size_t)jc * 8192 + i0 + w * 32 + 16 + lane] = lsB;
    }

    // f16 split-j partials; C/D layout row=q*4+reg, col=ci*16+l15
    _Float16* ap = ACCh + (size_t)jc * 2097152;
#pragma unroll
    for (int ci = 0; ci < 16; ++ci) {
#pragma unroll
        for (int reg = 0; reg < 4; ++reg) {
            int rowA = i0 + w * 32 + q * 4 + reg;
            ap[(size_t)rowA * 256 + ci * 16 + l15] = (_Float16)accA[ci][reg];
            ap[(size_t)(rowA + 16) * 256 + ci * 16 + l15] = (_Float16)accB[ci][reg];
        }
    }
}

// ---------------- K4: combine 16 partials, normalize, elu, f32 out ----------------
__global__ void k4_final(const _Float16* __restrict__ ACCh,
                         const float* __restrict__ Lp,
                         float* __restrict__ out) {
    int gid = blockIdx.x * 256 + threadIdx.x;   // 524288 threads x 4 elems
    int i = gid >> 6;
    float s0 = 0.f, s1 = 0.f, s2 = 0.f, s3 = 0.f;
#pragma unroll
    for (int jc = 0; jc < 16; ++jc) {
        h16x4 v = *(const h16x4*)(ACCh + (size_t)jc * 2097152 + (size_t)gid * 4);
        s0 += (float)v[0]; s1 += (float)v[1]; s2 += (float)v[2]; s3 += (float)v[3];
    }
    float L = 0.f;
#pragma unroll
    for (int jc = 0; jc < 16; ++jc) L += Lp[jc * 8192 + i];
    float inv = (L > 0.f) ? (1.0f / L) : 0.f;
    float h0 = s0 * inv, h1 = s1 * inv, h2 = s2 * inv, h3 = s3 * inv;
    float4 o;
    o.x = (h0 > 0.f) ? h0 : expm1f(h0);
    o.y = (h1 > 0.f) ? h1 : expm1f(h1);
    o.z = (h2 > 0.f) ? h2 : expm1f(h2);
    o.w = (h3 > 0.f) ? h3 : expm1f(h3);
    *(float4*)(out + (size_t)gid * 4) = o;
}

extern "C" void kernel_launch(void* const* d_in, const int* in_sizes, int n_in,
                              void* d_out, int out_size, void* d_ws, size_t ws_size,
                              hipStream_t stream) {
    (void)in_sizes; (void)n_in; (void)out_size; (void)ws_size;
    const float* X   = (const float*)d_in[0];
    const int*   adj = (const int*)d_in[1];
    const float* W   = (const float*)d_in[2];
    const float* a_s = (const float*)d_in[3];
    const float* a_d = (const float*)d_in[4];

    char* ws = (char*)d_ws;
    unsigned short* WTt  = (unsigned short*)(ws + OFF_WTT);
    unsigned short* WhTb = (unsigned short*)(ws + OFF_WHTB);
    float*          fsrc = (float*)(ws + OFF_FSRC);
    float*          fdst = (float*)(ws + OFF_FDST);
    unsigned int*   Mkey = (unsigned int*)(ws + OFF_MKEY);
    float*          Lp   = (float*)(ws + OFF_LP);
    _Float16*       ACCh = (_Float16*)(ws + OFF_ACCH);
    float*          out  = (float*)d_out;

    k0_init<<<dim3(256), dim3(256), 0, stream>>>(W, WTt, Mkey);
    k1_stage1<<<dim3(256), dim3(256), 0, stream>>>(X, WTt, a_s, a_d, WhTb, fsrc, fdst, Mkey);
    k2_fused<<<dim3(64, 16), dim3(256), 0, stream>>>(adj, WhTb, fsrc, fdst, Mkey, Lp, ACCh);
    k4_final<<<dim3(2048), dim3(256), 0, stream>>>(ACCh, Lp, out);
}

// Round 9
// 444.300 us; speedup vs baseline: 1.6989x; 1.6989x over previous
//
#include <hip/hip_runtime.h>
#include <stdint.h>

typedef __attribute__((ext_vector_type(8))) short short8;
typedef __attribute__((ext_vector_type(4))) float f32x4;
typedef __attribute__((ext_vector_type(4))) _Float16 h16x4;

#define LOG2E 1.4426950408889634f

// workspace layout (bytes) — ws ~1 GB, we use ~46.6 MB
#define OFF_WTT   0u          // W tiled bf16 [8][4][256][8]        = 131072
#define OFF_WHTB  131072u     // Wh tiled bf16 [256][4][256][8]     = 4194304
#define OFF_FSRC  12713984u   // f_src f32 [8192]
#define OFF_FDST  12746752u   // f_dst f32 [8192]
#define OFF_MKEY  12779520u   // max-key u32
#define OFF_LP    12779584u   // L partials f32 [8][8192]           = 262144
#define OFF_ACCH  13041728u   // ACC partials f16 [8][8192][256]    = 33554432

__device__ __forceinline__ unsigned short f2bf(float f) {
    union { float f; unsigned int i; } v; v.f = f;
    unsigned int u = v.i;
    return (unsigned short)((u + 0x7FFFu + ((u >> 16) & 1u)) >> 16);
}

// async global->LDS DMA, 16 B per lane (global_load_lds_dwordx4).
// lds ptr must be wave-uniform; HW adds lane*16.
__device__ __forceinline__ void stage16(const unsigned short* g, unsigned short* l) {
    __builtin_amdgcn_global_load_lds(
        (const __attribute__((address_space(1))) unsigned int*)g,
        (__attribute__((address_space(3))) unsigned int*)l,
        16, 0, 0);
}

// ---------------- K0: W (f32) -> tiled W^T (bf16), init max-key ----------------
__global__ void k0_init(const float* __restrict__ W,
                        unsigned short* __restrict__ WTt,
                        unsigned int* __restrict__ Mkey) {
    int idx = blockIdx.x * 256 + threadIdx.x;   // 65536 = i*256+o
    int i = idx >> 8, o = idx & 255;
    WTt[(i >> 5) * 8192 + ((i >> 3) & 3) * 2048 + o * 8 + (i & 7)] = f2bf(W[idx]);
    if (idx == 0) *Mkey = 0u;
}

// ---------------- K1: Wh = X@W, write tiled Wh (bf16), f_src/f_dst, global max ----
__global__ __launch_bounds__(256, 2)
void k1_stage1(const float* __restrict__ X,
               const unsigned short* __restrict__ WTt,
               const float* __restrict__ a_src,
               const float* __restrict__ a_dst,
               unsigned short* __restrict__ WhTb,
               float* __restrict__ f_src,
               float* __restrict__ f_dst,
               unsigned int* __restrict__ Mkey) {
    __shared__ __align__(16) unsigned short Bt[8192];   // 16 KB tile
    __shared__ float fsum[64];
    const int t = threadIdx.x, w = t >> 6, lane = t & 63, l15 = lane & 15, q = lane >> 4;
    const int rg = w & 1, cg = w >> 1;
    const int i0 = blockIdx.x * 32;
    const int arow = i0 + rg * 16 + l15;

    if (t < 64) fsum[t] = 0.f;

    float as[8], ad[8];
#pragma unroll
    for (int ci = 0; ci < 8; ++ci) {
        int col = cg * 128 + ci * 16 + l15;
        as[ci] = a_src[col]; ad[ci] = a_dst[col];
    }

    f32x4 acc[8];
#pragma unroll
    for (int ci = 0; ci < 8; ++ci) acc[ci] = (f32x4)0.f;

    for (int ks = 0; ks < 8; ++ks) {
        __syncthreads();
        {
            const uint4* src = (const uint4*)(WTt + ks * 8192);
            uint4* dst = (uint4*)Bt;
            dst[t] = src[t]; dst[256 + t] = src[256 + t];
            dst[512 + t] = src[512 + t]; dst[768 + t] = src[768 + t];
        }
        __syncthreads();
        const float* xp = X + (size_t)arow * 256 + ks * 32 + q * 8;
        float4 xa = *(const float4*)xp;
        float4 xb = *(const float4*)(xp + 4);
        short8 a;
        a[0] = (short)f2bf(xa.x); a[1] = (short)f2bf(xa.y);
        a[2] = (short)f2bf(xa.z); a[3] = (short)f2bf(xa.w);
        a[4] = (short)f2bf(xb.x); a[5] = (short)f2bf(xb.y);
        a[6] = (short)f2bf(xb.z); a[7] = (short)f2bf(xb.w);
#pragma unroll
        for (int ci = 0; ci < 8; ++ci) {
            short8 b = *(const short8*)((const char*)Bt + q * 4096 + (cg * 128 + ci * 16 + l15) * 16);
            acc[ci] = __builtin_amdgcn_mfma_f32_16x16x32_bf16(a, b, acc[ci], 0, 0, 0);
        }
    }

#pragma unroll
    for (int ci = 0; ci < 8; ++ci) {
        int col = cg * 128 + ci * 16 + l15;
        ushort4 v;
        v.x = f2bf(acc[ci][0]); v.y = f2bf(acc[ci][1]);
        v.z = f2bf(acc[ci][2]); v.w = f2bf(acc[ci][3]);
        size_t flat = (size_t)(i0 >> 5) * 8192 + (size_t)(rg * 2 + (q >> 1)) * 2048
                      + (size_t)col * 8 + (q & 1) * 4;
        *(ushort4*)(WhTb + flat) = v;
    }

#pragma unroll
    for (int reg = 0; reg < 4; ++reg) {
        float ps = 0.f, pd = 0.f;
#pragma unroll
        for (int ci = 0; ci < 8; ++ci) {
            ps += acc[ci][reg] * as[ci];
            pd += acc[ci][reg] * ad[ci];
        }
#pragma unroll
        for (int m = 1; m < 16; m <<= 1) {
            ps += __shfl_xor(ps, m, 64);
            pd += __shfl_xor(pd, m, 64);
        }
        if (l15 == 0) {
            atomicAdd(&fsum[rg * 16 + q * 4 + reg], ps);
            atomicAdd(&fsum[32 + rg * 16 + q * 4 + reg], pd);
        }
    }
    __syncthreads();
    if (t < 32) {
        int row = i0 + t;
        float ps = fsum[t], pd = fsum[32 + t];
        f_src[row] = ps;
        f_dst[row] = pd;
        union { float f; unsigned int u; } cv; cv.f = pd;
        unsigned int key = (cv.u & 0x80000000u) ? ~cv.u : (cv.u | 0x80000000u);
        atomicMax(Mkey, key);
    }
}

// ---------------- K2: fused mask+softmax+P@Wh, async-LDS double buffer (m97) ----
// grid (64 i-tiles x 8 j-chunks), 256 thr = 4 waves; wave = 32 rows x 256 cols.
// B tile (16 KB/js) DMA'd global->LDS one iter ahead via global_load_lds x4;
// B-frags via ds_read_b128; adj streamed HBM->regs in A-frag order.
__global__ __launch_bounds__(256, 2)
void k2_fused(const int* __restrict__ adj,
              const unsigned short* __restrict__ WhTb,
              const float* __restrict__ f_src,
              const float* __restrict__ f_dst,
              const unsigned int* __restrict__ Mkey,
              float* __restrict__ Lp,
              _Float16* __restrict__ ACCh) {
    __shared__ __align__(16) unsigned short Bt[2][8192];   // 32 KB double buffer
    __shared__ float fd_s[1024];                           // 4 KB
    const int t = threadIdx.x, w = t >> 6, lane = t & 63, l15 = lane & 15, q = lane >> 4;
    const int i0 = blockIdx.x * 128;
    const int jc = blockIdx.y;
    const int jb0 = jc * 1024;   // j base
    const int jw0 = jc * 32;     // 32-j tile base

    unsigned int key = *Mkey;
    union { unsigned int u; float f; } mv;
    mv.u = (key & 0x80000000u) ? (key & 0x7FFFFFFFu) : ~key;
    const float Mf = mv.f;
    const int rA = i0 + w * 32 + l15;
    const float fsA = f_src[rA], fsB = f_src[rA + 16];
    float vA = fsA + Mf; const float mcA = fmaxf(vA, 0.2f * vA) * LOG2E;
    float vB = fsB + Mf; const float mcB = fmaxf(vB, 0.2f * vB) * LOG2E;

    // stage fd chunk (1024 floats) + async-stage B tile 0 into buf 0
    { float4* d = (float4*)fd_s; d[t] = ((const float4*)(f_dst + jb0))[t]; }
    {
        const unsigned short* gsrc = WhTb + (size_t)jw0 * 8192;
#pragma unroll
        for (int s = 0; s < 4; ++s)
            stage16(gsrc + s * 2048 + t * 8, &Bt[0][s * 2048 + w * 512]);
    }

    const int* adjA = adj + (size_t)rA * 8192 + jb0 + q * 8;
    const int* adjB = adj + (size_t)(rA + 16) * 8192 + jb0 + q * 8;

    f32x4 accA[16], accB[16];
#pragma unroll
    for (int ci = 0; ci < 16; ++ci) { accA[ci] = (f32x4)0.f; accB[ci] = (f32x4)0.f; }
    float lsA = 0.f, lsB = 0.f;

    // prefetch js=0 adj
    int4 pA0 = *(const int4*)(adjA);
    int4 pA1 = *(const int4*)(adjA + 4);
    int4 pB0 = *(const int4*)(adjB);
    int4 pB1 = *(const int4*)(adjB + 4);
    __syncthreads();   // drains DMA (tile 0 ready) + fd_s

    for (int js = 0; js < 32; ++js) {
        const int buf = js & 1;
        const int jn = (js + 1) & 31;   // wrap: harmless redundant restage

        // ---- async stage next tile into other buffer ----
        {
            const unsigned short* gsrc = WhTb + (size_t)(jw0 + jn) * 8192;
#pragma unroll
            for (int s = 0; s < 4; ++s)
                stage16(gsrc + s * 2048 + t * 8, &Bt[buf ^ 1][s * 2048 + w * 512]);
        }

        // ---- P fragments from prefetched adj + LDS fd ----
        const float* fdp = fd_s + js * 32 + q * 8;
        float4 f0 = *(const float4*)fdp, f1 = *(const float4*)(fdp + 4);
        float fdv[8] = { f0.x, f0.y, f0.z, f0.w, f1.x, f1.y, f1.z, f1.w };
        int aAv[8] = { pA0.x, pA0.y, pA0.z, pA0.w, pA1.x, pA1.y, pA1.z, pA1.w };
        int aBv[8] = { pB0.x, pB0.y, pB0.z, pB0.w, pB1.x, pB1.y, pB1.z, pB1.w };
        short8 fragA, fragB;
#pragma unroll
        for (int k = 0; k < 8; ++k) {
            float tA = fsA + fdv[k];
            float eA = fmaxf(tA, 0.2f * tA);
            float pA = __builtin_amdgcn_exp2f(__builtin_fmaf(eA, LOG2E, -mcA));
            pA = (aAv[k] > 0) ? pA : 0.f;
            lsA += pA; fragA[k] = (short)f2bf(pA);
            float tB = fsB + fdv[k];
            float eB = fmaxf(tB, 0.2f * tB);
            float pB = __builtin_amdgcn_exp2f(__builtin_fmaf(eB, LOG2E, -mcB));
            pB = (aBv[k] > 0) ? pB : 0.f;
            lsB += pB; fragB[k] = (short)f2bf(pB);
        }

        // ---- prefetch next-iter adj (HBM latency hidden under MFMAs) ----
        pA0 = *(const int4*)(adjA + jn * 32);
        pA1 = *(const int4*)(adjA + jn * 32 + 4);
        pB0 = *(const int4*)(adjB + jn * 32);
        pB1 = *(const int4*)(adjB + jn * 32 + 4);

        // ---- MFMA from current LDS buffer (ds_read_b128, conflict-free) ----
        const char* base = (const char*)&Bt[buf][0] + q * 4096 + l15 * 16;
#pragma unroll
        for (int ci = 0; ci < 16; ++ci) {
            short8 bf = *(const short8*)(base + ci * 256);
            accA[ci] = __builtin_amdgcn_mfma_f32_16x16x32_bf16(fragA, bf, accA[ci], 0, 0, 0);
            accB[ci] = __builtin_amdgcn_mfma_f32_16x16x32_bf16(fragB, bf, accB[ci], 0, 0, 0);
        }

        __syncthreads();   // drains DMA (next tile ready) + orders LDS reuse
    }

    // row-sums: quads hold disjoint j; lanes 0-15 end with row totals
    lsA += __shfl_xor(lsA, 16, 64); lsA += __shfl_xor(lsA, 32, 64);
    lsB += __shfl_xor(lsB, 16, 64); lsB += __shfl_xor(lsB, 32, 64);
    if (lane < 16) {
        Lp[(size_t)jc * 8192 + i0 + w * 32 + lane] = lsA;
        Lp[(size_t)jc * 8192 + i0 + w * 32 + 16 + lane] = lsB;
    }

    // f16 split-j partials; C/D layout row=q*4+reg, col=ci*16+l15
    _Float16* ap = ACCh + (size_t)jc * 2097152;
#pragma unroll
    for (int ci = 0; ci < 16; ++ci) {
#pragma unroll
        for (int reg = 0; reg < 4; ++reg) {
            int rowA = i0 + w * 32 + q * 4 + reg;
            ap[(size_t)rowA * 256 + ci * 16 + l15] = (_Float16)accA[ci][reg];
            ap[(size_t)(rowA + 16) * 256 + ci * 16 + l15] = (_Float16)accB[ci][reg];
        }
    }
}

// ---------------- K4: combine 8 partials, normalize, elu, f32 out ----------------
__global__ void k4_final(const _Float16* __restrict__ ACCh,
                         const float* __restrict__ Lp,
                         float* __restrict__ out) {
    int gid = blockIdx.x * 256 + threadIdx.x;   // 524288 threads x 4 elems
    int i = gid >> 6;
    float s0 = 0.f, s1 = 0.f, s2 = 0.f, s3 = 0.f;
#pragma unroll
    for (int jc = 0; jc < 8; ++jc) {
        h16x4 v = *(const h16x4*)(ACCh + (size_t)jc * 2097152 + (size_t)gid * 4);
        s0 += (float)v[0]; s1 += (float)v[1]; s2 += (float)v[2]; s3 += (float)v[3];
    }
    float L = 0.f;
#pragma unroll
    for (int jc = 0; jc < 8; ++jc) L += Lp[jc * 8192 + i];
    float inv = (L > 0.f) ? (1.0f / L) : 0.f;
    float h0 = s0 * inv, h1 = s1 * inv, h2 = s2 * inv, h3 = s3 * inv;
    float4 o;
    o.x = (h0 > 0.f) ? h0 : expm1f(h0);
    o.y = (h1 > 0.f) ? h1 : expm1f(h1);
    o.z = (h2 > 0.f) ? h2 : expm1f(h2);
    o.w = (h3 > 0.f) ? h3 : expm1f(h3);
    *(float4*)(out + (size_t)gid * 4) = o;
}

extern "C" void kernel_launch(void* const* d_in, const int* in_sizes, int n_in,
                              void* d_out, int out_size, void* d_ws, size_t ws_size,
                              hipStream_t stream) {
    (void)in_sizes; (void)n_in; (void)out_size; (void)ws_size;
    const float* X   = (const float*)d_in[0];
    const int*   adj = (const int*)d_in[1];
    const float* W   = (const float*)d_in[2];
    const float* a_s = (const float*)d_in[3];
    const float* a_d = (const float*)d_in[4];

    char* ws = (char*)d_ws;
    unsigned short* WTt  = (unsigned short*)(ws + OFF_WTT);
    unsigned short* WhTb = (unsigned short*)(ws + OFF_WHTB);
    float*          fsrc = (float*)(ws + OFF_FSRC);
    float*          fdst = (float*)(ws + OFF_FDST);
    unsigned int*   Mkey = (unsigned int*)(ws + OFF_MKEY);
    float*          Lp   = (float*)(ws + OFF_LP);
    _Float16*       ACCh = (_Float16*)(ws + OFF_ACCH);
    float*          out  = (float*)d_out;

    k0_init<<<dim3(256), dim3(256), 0, stream>>>(W, WTt, Mkey);
    k1_stage1<<<dim3(256), dim3(256), 0, stream>>>(X, WTt, a_s, a_d, WhTb, fsrc, fdst, Mkey);
    k2_fused<<<dim3(64, 8), dim3(256), 0, stream>>>(adj, WhTb, fsrc, fdst, Mkey, Lp, ACCh);
    k4_final<<<dim3(2048), dim3(256), 0, stream>>>(ACCh, Lp, out);
}